// Round 1
// 978.369 us; speedup vs baseline: 1.0644x; 1.0644x over previous
//
#include <hip/hip_runtime.h>
#include <stdint.h>

// Problem: B=64, T=256, F_IN=2048, H=1024, 3H=3072, M=B*T=16384.
// d_out: output f32[64,256,1024] then hidden f32[64,1024]

typedef __bf16 bfx8 __attribute__((ext_vector_type(8)));
typedef float  f32x4 __attribute__((ext_vector_type(4)));
typedef unsigned u32x4 __attribute__((ext_vector_type(4)));
typedef unsigned long long ull;

// ---------------- fp32 -> bf16 conversion (8 elems/thread) ----------------
__global__ void cvt_bf16(const float* __restrict__ in, __bf16* __restrict__ out, int n8) {
    for (int i = blockIdx.x * blockDim.x + threadIdx.x; i < n8; i += gridDim.x * blockDim.x) {
        float4 a = ((const float4*)in)[2 * i];
        float4 b = ((const float4*)in)[2 * i + 1];
        union { __bf16 h[8]; uint4 v; } u;
        u.h[0] = (__bf16)a.x; u.h[1] = (__bf16)a.y; u.h[2] = (__bf16)a.z; u.h[3] = (__bf16)a.w;
        u.h[4] = (__bf16)b.x; u.h[5] = (__bf16)b.y; u.h[6] = (__bf16)b.z; u.h[7] = (__bf16)b.w;
        ((uint4*)out)[i] = u.v;
    }
}

// ---------------- async global->LDS 16B ----------------
__device__ __forceinline__ void g2l16(const void* g, void* l) {
    __builtin_amdgcn_global_load_lds(
        (__attribute__((address_space(1))) void*)g,
        (__attribute__((address_space(3))) void*)l,
        16, 0, 0);
}

// ================= 256x256-tile 8-phase bf16 GEMM =================
// C[M][N] = A[M][K] * W[N][K]^T + bias.  512 thr = 8 waves (2M x 4N),
// BK=64, LDS 128KB: A [2buf][2half][128 rows][64 bf16], B same at +64KB.
// Swizzle (both-sides, involution): byte ^= ((row&7)<<4)  -- each 16-lane
// quad of a b128 fragment read hits 8 distinct 16B slots (2 lanes/bank).
// Staging: pre-swizzled GLOBAL source + linear global_load_lds dest (m173).
// Schedule per K-tile t (buf = t&1):
//   ph1: ds a0(8)+b01(4) | bar | lgkm0 | prio1 16xMFMA prio0 | bar
//   ph2: ds b23(4) | stage B(t+2) | bar | lgkm0 | 16xMFMA | bar
//   ph3: ds a1(8) | stage A(t+2) | bar | lgkm0 | 16xMFMA | bar
//   ph4: vmcnt(8)  (last 2 tiles: vmcnt(0)) | bar | 16xMFMA | bar
// Invariant: tile T+2's 4 halves issued in T's ph2/ph3 (after last
// program-order read of that buffer region); vmcnt(8) at T's ph4 leaves only
// those 8 loads outstanding => tile T+1 fully landed before its ph1 reads.

__device__ __forceinline__ void stage_half16(const char* mat, int row0, size_t Kb, int tk,
                                             char* ldsHalf, int sr, int scb, int wave) {
    // chunk c = rd*512 + tid; LDS dest linear c*16; global src = unswizzled
    // position of swz(c*16): row = rd*64 + (tid>>3), colbyte = ((tid^(tid>>3))&7)<<4
    const char* s0 = mat + (size_t)(row0 + sr) * Kb + ((size_t)tk << 7) + scb;
    g2l16(s0, ldsHalf + (wave << 10));
    g2l16(s0 + (Kb << 6), ldsHalf + 8192 + (wave << 10));   // +64 rows
}

#define MFMA16 __builtin_amdgcn_mfma_f32_16x16x32_bf16

template <bool OUTBF16>
__global__ __launch_bounds__(512)
void gemm256(const __bf16* __restrict__ A, const __bf16* __restrict__ W,
             const float* __restrict__ bias, void* __restrict__ C,
             int M, int N, int K)
{
    __shared__ char smem[131072];
    const int tid  = threadIdx.x;
    const int wave = tid >> 6, lane = tid & 63;
    const int q = lane >> 4, r15 = lane & 15;
    const int wm = wave >> 2, wn = wave & 3;          // 2 x 4 wave grid

    // bijective XCD swizzle (nwg % 8 == 0 for both our launches)
    const int nbx = N >> 8;
    const int nwg = (M >> 8) * nbx;
    const int cpx = nwg >> 3;
    const int wg  = (blockIdx.x & 7) * cpx + (blockIdx.x >> 3);
    const int m0  = (wg / nbx) << 8, n0 = (wg % nbx) << 8;
    const size_t Kb = (size_t)K << 1;                 // row bytes
    const int NT = K >> 6;                            // K-tiles (even, >=4)

    // staging source precompute (per lane)
    const int sr  = tid >> 3;                          // row 0..63 (round0)
    const int scb = ((tid ^ (tid >> 3)) & 7) << 4;     // swizzled 16B slot
    // ds_read lane offsets: row r15, slot (ks*4+q) ^ (r15&7)
    const int sx  = r15 & 7;
    const int la0 = r15 * 128 + ((q ^ sx) << 4);       // ks=0
    const int la1 = r15 * 128 + (((q | 4) ^ sx) << 4); // ks=1

    const char* Ac = (const char*)A;
    const char* Wc = (const char*)W;

    // ---- prologue: stage tiles 0 and 1 (16 instr/wave), tile0 landed ----
#pragma unroll
    for (int t = 0; t < 2; ++t) {
        char* ab = smem + (t << 15);
        char* bb = smem + 65536 + (t << 15);
        stage_half16(Ac, m0,       Kb, t, ab,         sr, scb, wave);
        stage_half16(Ac, m0 + 128, Kb, t, ab + 16384, sr, scb, wave);
        stage_half16(Wc, n0,       Kb, t, bb,         sr, scb, wave);
        stage_half16(Wc, n0 + 128, Kb, t, bb + 16384, sr, scb, wave);
    }
    asm volatile("s_waitcnt vmcnt(8)" ::: "memory");
    __builtin_amdgcn_s_barrier();

    f32x4 acc[8][4] = {};

    for (int t = 0; t < NT; ++t) {
        const int bsel = t & 1;
        const char* Ab = smem + (bsel << 15) + (wm << 14);
        const char* Bb = smem + 65536 + (bsel << 15) + ((wn >> 1) << 14) + ((wn & 1) << 13);
        const int t2 = t + 2;
        const bool st = t2 < NT;

        bfx8 aw[4][2], b01[2][2], b23[2][2];

        // ---- phase 1: a0 + b01, MFMA m0-3 x n0-1 ----
#pragma unroll
        for (int m = 0; m < 4; ++m) {
            aw[m][0] = *(const bfx8*)(Ab + (m << 11) + la0);
            aw[m][1] = *(const bfx8*)(Ab + (m << 11) + la1);
        }
#pragma unroll
        for (int n = 0; n < 2; ++n) {
            b01[n][0] = *(const bfx8*)(Bb + (n << 11) + la0);
            b01[n][1] = *(const bfx8*)(Bb + (n << 11) + la1);
        }
        __builtin_amdgcn_s_barrier();
        asm volatile("s_waitcnt lgkmcnt(0)" ::: "memory");
        __builtin_amdgcn_s_setprio(1);
#pragma unroll
        for (int m = 0; m < 4; ++m)
#pragma unroll
            for (int n = 0; n < 2; ++n) {
                acc[m][n] = MFMA16(aw[m][0], b01[n][0], acc[m][n], 0, 0, 0);
                acc[m][n] = MFMA16(aw[m][1], b01[n][1], acc[m][n], 0, 0, 0);
            }
        __builtin_amdgcn_s_setprio(0);
        __builtin_amdgcn_s_barrier();

        // ---- phase 2: b23, stage B(t+2), MFMA m0-3 x n2-3 ----
#pragma unroll
        for (int n = 0; n < 2; ++n) {
            b23[n][0] = *(const bfx8*)(Bb + ((n + 2) << 11) + la0);
            b23[n][1] = *(const bfx8*)(Bb + ((n + 2) << 11) + la1);
        }
        if (st) {
            char* bb = smem + 65536 + (bsel << 15);   // (t+2)&1 == bsel
            stage_half16(Wc, n0,       Kb, t2, bb,         sr, scb, wave);
            stage_half16(Wc, n0 + 128, Kb, t2, bb + 16384, sr, scb, wave);
        }
        __builtin_amdgcn_s_barrier();
        asm volatile("s_waitcnt lgkmcnt(0)" ::: "memory");
        __builtin_amdgcn_s_setprio(1);
#pragma unroll
        for (int m = 0; m < 4; ++m)
#pragma unroll
            for (int n = 0; n < 2; ++n) {
                acc[m][n + 2] = MFMA16(aw[m][0], b23[n][0], acc[m][n + 2], 0, 0, 0);
                acc[m][n + 2] = MFMA16(aw[m][1], b23[n][1], acc[m][n + 2], 0, 0, 0);
            }
        __builtin_amdgcn_s_setprio(0);
        __builtin_amdgcn_s_barrier();

        // ---- phase 3: a1, stage A(t+2), MFMA m4-7 x n2-3 ----
#pragma unroll
        for (int m = 0; m < 4; ++m) {
            aw[m][0] = *(const bfx8*)(Ab + 8192 + (m << 11) + la0);
            aw[m][1] = *(const bfx8*)(Ab + 8192 + (m << 11) + la1);
        }
        if (st) {
            char* ab = smem + (bsel << 15);
            stage_half16(Ac, m0,       Kb, t2, ab,         sr, scb, wave);
            stage_half16(Ac, m0 + 128, Kb, t2, ab + 16384, sr, scb, wave);
        }
        __builtin_amdgcn_s_barrier();
        asm volatile("s_waitcnt lgkmcnt(0)" ::: "memory");
        __builtin_amdgcn_s_setprio(1);
#pragma unroll
        for (int m = 0; m < 4; ++m)
#pragma unroll
            for (int n = 0; n < 2; ++n) {
                acc[m + 4][n + 2] = MFMA16(aw[m][0], b23[n][0], acc[m + 4][n + 2], 0, 0, 0);
                acc[m + 4][n + 2] = MFMA16(aw[m][1], b23[n][1], acc[m + 4][n + 2], 0, 0, 0);
            }
        __builtin_amdgcn_s_setprio(0);
        __builtin_amdgcn_s_barrier();

        // ---- phase 4: counted vmcnt, MFMA m4-7 x n0-1 ----
        if (t < NT - 2) asm volatile("s_waitcnt vmcnt(8)" ::: "memory");
        else            asm volatile("s_waitcnt vmcnt(0)" ::: "memory");
        __builtin_amdgcn_s_barrier();
        __builtin_amdgcn_s_setprio(1);
#pragma unroll
        for (int m = 0; m < 4; ++m)
#pragma unroll
            for (int n = 0; n < 2; ++n) {
                acc[m + 4][n] = MFMA16(aw[m][0], b01[n][0], acc[m + 4][n], 0, 0, 0);
                acc[m + 4][n] = MFMA16(aw[m][1], b01[n][1], acc[m + 4][n], 0, 0, 0);
            }
        __builtin_amdgcn_s_setprio(0);
        __builtin_amdgcn_s_barrier();
    }

    // ---- epilogue: bias + store ----
#pragma unroll
    for (int nf = 0; nf < 4; ++nf) {
        const int col = n0 + (wn << 6) + (nf << 4) + r15;
        const float bv = bias[col];
#pragma unroll
        for (int mf = 0; mf < 8; ++mf) {
#pragma unroll
            for (int i = 0; i < 4; ++i) {
                const int row = m0 + (wm << 7) + (mf << 4) + (q << 2) + i;
                const float v = acc[mf][nf][i] + bv;
                if (OUTBF16) ((__bf16*)C)[(size_t)row * N + col] = (__bf16)v;
                else         ((float*)C)[(size_t)row * N + col]  = v;
            }
        }
    }
}

// ---------------- GRU recurrence: persistent cooperative kernel ----------------
// 256 blocks = 4 batch-groups (bb, 16 batches, XCD pair) x 64 H-slices (bj).
// (unchanged from R6 -- sync model proven; see session notes)
__device__ __forceinline__ float sigm(float x) { return 1.f / (1.f + __expf(-x)); }
__device__ __forceinline__ float tanh_f(float x) { float e = __expf(2.f * x); return 1.f - 2.f / (e + 1.f); }

#define RP 1032  // padded LDS row stride in bf16 (2064 B; 16B-pad => 2-way banks, free)

__global__ __launch_bounds__(256, 1)
void rnn_kernel(const float* __restrict__ gx, const int* __restrict__ lens,
                const __bf16* __restrict__ whhb, const float* __restrict__ b_hh,
                char* __restrict__ hbuf,         // [2][64][1024] bf16 = 256KB, zeroed
                float* __restrict__ out,         // B*T*H then B*H
                unsigned* __restrict__ flags)    // 256 flags, 64B apart, zeroed
{
    __shared__ __bf16 hs[16 * RP];               // staged h: 16 batches x 1024 (33KB)
    __shared__ float  ghs2[3 * 4 * 256];         // gate partials [g][wave][m*16+n] (12KB)

    const int tid  = threadIdx.x;
    const int wave = tid >> 6, lane = tid & 63;
    const int q = lane >> 4, r15 = lane & 15;
    const int bb = (blockIdx.x & 7) >> 1;                         // batch group (XCD pair)
    const int bj = ((blockIdx.x >> 3) << 1) | (blockIdx.x & 1);   // unit slice 0..63

    // ---- one-time: w_hh B-fragments into registers ----
    bfx8 Bf[3][8];
#pragma unroll
    for (int g = 0; g < 3; ++g)
#pragma unroll
        for (int kk = 0; kk < 8; ++kk)
            Bf[g][kk] = *(const bfx8*)(whhb
                + ((size_t)((g << 10) + (bj << 4) + r15) << 10)
                + (wave << 8) + (kk << 5) + (q << 3));

    const int m_ = tid >> 4, jj_ = tid & 15;
    const int bglob = (bb << 4) + m_;
    const int jglob = (bj << 4) + jj_;
    const float bhr = b_hh[jglob], bhz = b_hh[1024 + jglob], bhn = b_hh[2048 + jglob];
    const int mylen = lens[bglob];
    const int pd   = (tid & 127) >> 1;
    const int pblk = ((pd >> 1) << 3) | (bb << 1) | (pd & 1);
    const unsigned* fpoll = &flags[pblk << 4];

    const float* gp = gx + (size_t)bglob * 256 * 3072 + jglob;
    float gir = gp[0], giz = gp[1024], gin = gp[2048];   // gx for t=0
    float hstate = 0.f;

    for (int t = 0; t < 256; ++t) {
        // ---- per-thread: wait own producer, then stage its 8 chunks (sc1) ----
        if (t > 0) {
            unsigned tgt = (unsigned)t;
            while (__hip_atomic_load(fpoll, __ATOMIC_RELAXED, __HIP_MEMORY_SCOPE_AGENT) < tgt)
                __builtin_amdgcn_s_sleep(1);
            asm volatile("" ::: "memory");
        }
        {
            const char* sb = hbuf + ((t & 1) << 17) + (bb << 15) + (tid << 4);
            u32x4 r0, r1, r2, r3, r4, r5, r6, r7;
            asm volatile(
                "global_load_dwordx4 %0, %8, off sc1\n\t"
                "global_load_dwordx4 %1, %9, off sc1\n\t"
                "global_load_dwordx4 %2, %10, off sc1\n\t"
                "global_load_dwordx4 %3, %11, off sc1\n\t"
                "global_load_dwordx4 %4, %12, off sc1\n\t"
                "global_load_dwordx4 %5, %13, off sc1\n\t"
                "global_load_dwordx4 %6, %14, off sc1\n\t"
                "global_load_dwordx4 %7, %15, off sc1\n\t"
                "s_waitcnt vmcnt(0)"
                : "=&v"(r0), "=&v"(r1), "=&v"(r2), "=&v"(r3),
                  "=&v"(r4), "=&v"(r5), "=&v"(r6), "=&v"(r7)
                : "v"(sb),          "v"(sb + 4096),  "v"(sb + 8192),  "v"(sb + 12288),
                  "v"(sb + 16384),  "v"(sb + 20480), "v"(sb + 24576), "v"(sb + 28672)
                : "memory");
            const int colb = (tid & 127) << 4;
            const int mh = tid >> 7;
            char* hsb = (char*)hs;
            *(u32x4*)(hsb + (2 * 0 + mh) * 2064 + colb) = r0;
            *(u32x4*)(hsb + (2 * 1 + mh) * 2064 + colb) = r1;
            *(u32x4*)(hsb + (2 * 2 + mh) * 2064 + colb) = r2;
            *(u32x4*)(hsb + (2 * 3 + mh) * 2064 + colb) = r3;
            *(u32x4*)(hsb + (2 * 4 + mh) * 2064 + colb) = r4;
            *(u32x4*)(hsb + (2 * 5 + mh) * 2064 + colb) = r5;
            *(u32x4*)(hsb + (2 * 6 + mh) * 2064 + colb) = r6;
            *(u32x4*)(hsb + (2 * 7 + mh) * 2064 + colb) = r7;
        }
        __syncthreads();  // barB: h staged

        // ---- all 4 waves: K-chunk = wave*256, 3 gates, 8-deep pipelined chains ----
        {
            f32x4 a0 = {0.f, 0.f, 0.f, 0.f}, a1 = a0, a2 = a0;
            const __bf16* hrow = &hs[r15 * RP + (wave << 8)];
#pragma unroll
            for (int kk = 0; kk < 8; ++kk) {
                bfx8 a = *(const bfx8*)(hrow + (kk << 5) + (q << 3));
                a0 = __builtin_amdgcn_mfma_f32_16x16x32_bf16(a, Bf[0][kk], a0, 0, 0, 0);
                a1 = __builtin_amdgcn_mfma_f32_16x16x32_bf16(a, Bf[1][kk], a1, 0, 0, 0);
                a2 = __builtin_amdgcn_mfma_f32_16x16x32_bf16(a, Bf[2][kk], a2, 0, 0, 0);
            }
#pragma unroll
            for (int i2 = 0; i2 < 4; ++i2) {
                int di = (((q << 2) + i2) << 4) + r15;   // m*16 + n
                ghs2[(wave << 8) + di]        = a0[i2];
                ghs2[1024 + (wave << 8) + di] = a1[i2];
                ghs2[2048 + (wave << 8) + di] = a2[i2];
            }
        }
        __syncthreads();  // barC: partials ready

        // ---- reduce 4 partials + gates; thread <-> (batch m_, unit jj_) ----
        float ghr = ghs2[tid] + ghs2[256 + tid] + ghs2[512 + tid] + ghs2[768 + tid] + bhr;
        float ghz = ghs2[1024 + tid] + ghs2[1280 + tid] + ghs2[1536 + tid] + ghs2[1792 + tid] + bhz;
        float ghn = ghs2[2048 + tid] + ghs2[2304 + tid] + ghs2[2560 + tid] + ghs2[2816 + tid] + bhn;
        float rg = sigm(gir + ghr);
        float zg = sigm(giz + ghz);
        float ng = tanh_f(gin + rg * ghn);
        float hnew = (1.f - zg) * ng + zg * hstate;
        bool mk = t < mylen;
        hstate = mk ? hnew : hstate;
        float y = mk ? hnew : 0.f;

        if (t < 255) {
            // ---- publish: pair-pack via shfl, even lanes one 4B coherent store ----
            union { unsigned short us; __bf16 h; } cv; cv.h = (__bf16)hstate;
            unsigned hb = cv.us;
            unsigned nb = (unsigned)__shfl_xor((int)hb, 1);
            if (!(tid & 1)) {
                unsigned dv = hb | (nb << 16);
                unsigned* hw = (unsigned*)(hbuf + (((t + 1) & 1) << 17)
                             + (bglob << 11) + ((bj << 4) + jj_) * 2);
                __hip_atomic_store(hw, dv, __ATOMIC_RELAXED, __HIP_MEMORY_SCOPE_AGENT);
            }
            __syncthreads();  // barA: per-wave vmcnt(0) => all h stores acked at LLC
            if (tid == 0)
                __hip_atomic_store(&flags[blockIdx.x << 4], (unsigned)(t + 1),
                                   __ATOMIC_RELAXED, __HIP_MEMORY_SCOPE_AGENT);
            // out store + gx(t+1) prefetch: drain under next poll/stage window
            out[(size_t)(bglob * 256 + t) * 1024 + jglob] = y;
            gp += 3072;
            gir = gp[0]; giz = gp[1024]; gin = gp[2048];
        } else {
            out[(size_t)(bglob * 256 + t) * 1024 + jglob] = y;
            out[(size_t)(64 * 256) * 1024 + ((size_t)bglob << 10) + jglob] = y;  // hidden
        }
    }
}

// ---------------- launch ----------------
extern "C" void kernel_launch(void* const* d_in, const int* in_sizes, int n_in,
                              void* d_out, int out_size, void* d_ws, size_t ws_size,
                              hipStream_t stream) {
    const float* input = (const float*)d_in[0];
    const int*   lens  = (const int*)d_in[1];
    const float* W_p   = (const float*)d_in[2];
    const float* b_p   = (const float*)d_in[3];
    const float* w_ih  = (const float*)d_in[4];
    const float* w_hh  = (const float*)d_in[5];
    const float* b_ih  = (const float*)d_in[6];
    const float* b_hh  = (const float*)d_in[7];
    float* out = (float*)d_out;
    char* ws = (char*)d_ws;

    // workspace layout (bytes): total ~319 MB
    __bf16* Xb   = (__bf16*)(ws + 0);            // 67,108,864
    __bf16* Wpb  = (__bf16*)(ws + 67108864);     //  4,194,304
    __bf16* wihb = (__bf16*)(ws + 71303168);     //  6,291,456
    __bf16* whhb = (__bf16*)(ws + 77594624);     //  6,291,456
    __bf16* embb = (__bf16*)(ws + 83886080);     // 33,554,432
    float*  gx   = (float*) (ws + 117440512);    // 201,326,592
    char* hbuf   = ws + 318767104;               // 262,144 (double-buffered h)
    unsigned* flags = (unsigned*)(ws + 319029248); // 256 x 64B = 16,384

    // zero h state + flags (d_ws is poisoned 0xAA before every launch)
    hipMemsetAsync(ws + 318767104, 0, 262144 + 16384, stream);

    cvt_bf16<<<4096, 256, 0, stream>>>(input, Xb, 33554432 / 8);
    cvt_bf16<<<1024, 256, 0, stream>>>(W_p,  Wpb, 2097152 / 8);
    cvt_bf16<<<1536, 256, 0, stream>>>(w_ih, wihb, 3145728 / 8);
    cvt_bf16<<<1536, 256, 0, stream>>>(w_hh, whhb, 3145728 / 8);

    // emb = X @ W_p^T + b_p  (bf16 out), M=16384 N=1024 K=2048 -> 256 wgs
    gemm256<true><<<dim3(256), 512, 0, stream>>>(Xb, Wpb, b_p, embb, 16384, 1024, 2048);
    // gx = emb @ w_ih^T + b_ih (f32 out), M=16384 N=3072 K=1024 -> 768 wgs
    gemm256<false><<<dim3(768), 512, 0, stream>>>(embb, wihb, b_ih, gx, 16384, 3072, 1024);

    // recurrence: 256 blocks (1 block/CU, co-resident), 256 steps
    rnn_kernel<<<256, 256, 0, stream>>>(gx, lens, whhb, b_hh, hbuf, out, flags);
}